// Round 3
// baseline (4440.409 us; speedup 1.0000x reference)
//
#include <hip/hip_runtime.h>
#include <hip/hip_bf16.h>

#define TT 128
#define BB 128
#define HH 1024
#define PP 32
#define G7 7168

typedef __attribute__((ext_vector_type(8))) short short8;
typedef __attribute__((ext_vector_type(4))) float f32x4;

__device__ __forceinline__ ushort f2bf(float f) {
    union { float f; unsigned int u; } v; v.f = f;
    unsigned int u = v.u;
    return (ushort)((u + 0x7FFFu + ((u >> 16) & 1u)) >> 16);
}
__device__ __forceinline__ float sigm(float x) { return 1.f / (1.f + __expf(-x)); }
__device__ __forceinline__ float ftanh(float x) {
    float e = __expf(2.f * x);
    return 1.f - 2.f / (e + 1.f);
}

// ---- prep: repack W rows 32..1055 into MFMA-fragment-major bf16 layout ----
// W2[(nt*32 + ki)*64 + lane][e] = W[32 + ki*32 + (lane>>4)*8 + e][nt*16 + (lane&15)]
__global__ void prep_w2(const float* __restrict__ W, ushort* __restrict__ W2) {
    int nt = blockIdx.x;          // 0..447 (n-tile of 16 cols)
    int ki = blockIdx.y;          // 0..31  (k-chunk of 32)
    int lane = threadIdx.x;       // 0..63
    int n = nt * 16 + (lane & 15);
    int k = ki * 32 + (lane >> 4) * 8;
    size_t off = ((size_t)(nt * 32 + ki) * 64 + lane) * 8;
    #pragma unroll
    for (int e = 0; e < 8; ++e)
        W2[off + e] = f2bf(W[(size_t)(32 + k + e) * G7 + n]);
}

// ---- prep: G0[type][n] = b[n] + embed[type] @ W[0:32] ----
__global__ void prep_g0(const float* __restrict__ W, const float* __restrict__ embed,
                        const float* __restrict__ bias, float* __restrict__ G0) {
    int n = blockIdx.x * 256 + threadIdx.x;
    int ty = blockIdx.y;
    float acc = bias[n];
    for (int p = 0; p < PP; ++p)
        acc += embed[ty * PP + p] * W[(size_t)p * G7 + n];
    G0[(size_t)ty * G7 + n] = acc;
}

// ---- prep: init states; h0 into ki-major fragment layout A3 ----
// A3[((k>>5)*8 + (b>>4))*64 + lane][e], lane = (b&15)|(((k>>3)&3)<<4), e = k&7
__global__ void prep_init(const float* __restrict__ h0, const float* __restrict__ c0,
                          ushort* __restrict__ A3, float* __restrict__ c_state,
                          float* __restrict__ ctgt_state) {
    int i = blockIdx.x * 256 + threadIdx.x;  // over 128*1024
    int b = i >> 10, k = i & 1023;
    int lane = (b & 15) | (((k >> 3) & 3) << 4);
    size_t off = ((size_t)((k >> 5) * 8 + (b >> 4)) * 64 + lane) * 8 + (k & 7);
    A3[off] = f2bf(h0[i]);
    c_state[i] = c0[i];
    ctgt_state[i] = c0[i];
}

// ---- per-step fused kernel: 64 blocks (XCD-pinned h-slices), 7 gate-waves,
// each wave: ALL 128 batch rows (8 b-frags) x 16 h-cols. W read ONCE per step. ----
__global__ __launch_bounds__(448) void step_kernel(
    const ushort* __restrict__ W2, const float* __restrict__ G0,
    const float* __restrict__ dts, const int* __restrict__ types,
    const ushort* __restrict__ a_read, ushort* __restrict__ a_write,
    float* __restrict__ c_state, float* __restrict__ ctgt_state,
    float* __restrict__ out, int t)
{
    __shared__ float gbuf[7][128][16];
    const int tid = threadIdx.x;
    const int g = tid >> 6;            // gate = wave 0..6
    const int lane = tid & 63;
    // XCD-pin: bid&7 = XCD under round-robin dispatch; XCD x serves h-cols [x*128, x*128+128)
    const int bid = blockIdx.x;
    const int ht = (bid & 7) * 8 + (bid >> 3);   // h-tile 0..63
    const int h0i = ht * 16;
    const int nt = g * 64 + ht;

    const short8* Av = reinterpret_cast<const short8*>(a_read) + lane;
    const short8* Wv = reinterpret_cast<const short8*>(W2) + (size_t)nt * 2048 + lane;

    f32x4 acc[8] = {};

    // k-loop: 32 ki steps; barrier every 4 ki keeps the 7 waves within a 32 KB
    // A-window so waves 1..6 hit L1 on the shared A-frag lines.
    for (int kc = 0; kc < 8; ++kc) {
        #pragma unroll
        for (int ku = 0; ku < 4; ++ku) {
            const int ki = kc * 4 + ku;
            short8 wf = Wv[ki * 64];
            const short8* ap = Av + ki * 512;
            #pragma unroll
            for (int bf = 0; bf < 8; ++bf) {
                short8 af = ap[bf * 64];
                acc[bf] = __builtin_amdgcn_mfma_f32_16x16x32_bf16(af, wf, acc[bf], 0, 0, 0);
            }
        }
        __syncthreads();
    }

    // C/D layout (harness-verified in R2): b-row = (lane>>4)*4 + r, h-col = lane&15
    const int rb = (lane >> 4) * 4;
    const int lr = lane & 15;
    #pragma unroll
    for (int bf = 0; bf < 8; ++bf) {
        #pragma unroll
        for (int r = 0; r < 4; ++r)
            gbuf[g][bf * 16 + rb + r][lr] = acc[bf][r];
    }
    __syncthreads();

    const size_t OS = (size_t)TT * BB * HH;
    for (int e = tid; e < 2048; e += 448) {
        int b = e >> 4;             // 0..127
        int hc = e & 15;
        int h = h0i + hc;
        int ty = types[t * BB + b];
        float dt = dts[t * BB + b];
        const float* g0p = G0 + (size_t)ty * G7 + h;
        float pre[7];
        #pragma unroll
        for (int gg = 0; gg < 7; ++gg)
            pre[gg] = gbuf[gg][b][hc] + g0p[gg * HH];

        float inpt   = sigm(pre[0]);
        float forget = sigm(pre[1]);
        float output = sigm(pre[2]);
        float itg    = sigm(pre[3]);
        float ftg    = sigm(pre[4]);
        float z      = ftanh(pre[5]);
        float x8     = 8.f * pre[6];
        float sp     = fmaxf(x8, 0.f) + __logf(1.f + __expf(-fabsf(x8)));
        float decay  = sp * 0.125f;

        size_t si = (size_t)b * HH + h;
        float c    = c_state[si];
        float ctgt = ctgt_state[si];
        float c_i      = forget * c + inpt * z;
        float h_i      = output * ftanh(c_i);
        float ctgt_new = ftg * ctgt + itg * z;
        float edt      = __expf(-decay * dt);
        float c_new    = ctgt_new + (c_i - ctgt_new) * edt;
        float h_new    = output * ftanh(c_new);

        size_t ob = (size_t)t * BB * HH + si;
        out[ob]          = h_i;
        out[OS + ob]     = h_new;
        out[2 * OS + ob] = output;
        out[3 * OS + ob] = c_i;
        out[4 * OS + ob] = ctgt_new;
        out[5 * OS + ob] = decay;
        c_state[si]    = c_new;
        ctgt_state[si] = ctgt_new;
        // h_new -> next step's A3 (ki-major fragment layout)
        int lane_w = (b & 15) | (((h >> 3) & 3) << 4);
        size_t aoff = ((size_t)((h >> 5) * 8 + (b >> 4)) * 64 + lane_w) * 8 + (h & 7);
        a_write[aoff] = f2bf(h_new);
    }
}

extern "C" void kernel_launch(void* const* d_in, const int* in_sizes, int n_in,
                              void* d_out, int out_size, void* d_ws, size_t ws_size,
                              hipStream_t stream) {
    const float* seq_dt    = (const float*)d_in[0];
    const int*   seq_types = (const int*)d_in[1];
    const float* h0        = (const float*)d_in[2];
    const float* c0        = (const float*)d_in[3];
    const float* embed     = (const float*)d_in[4];
    const float* W         = (const float*)d_in[5];
    const float* bias      = (const float*)d_in[6];
    float* out = (float*)d_out;

    char* ws = (char*)d_ws;
    ushort* W2        = (ushort*)ws;                 // 7168*1024*2 = 14,680,064
    float*  G0        = (float*)(ws + 14680064);     // 33*7168*4  =    946,176
    ushort* hs0       = (ushort*)(ws + 15626240);    // 128*1024*2 =    262,144
    ushort* hs1       = (ushort*)(ws + 15888384);    //                 262,144
    float*  c_state   = (float*)(ws + 16150528);     // 128*1024*4 =    524,288
    float*  ctgt_state= (float*)(ws + 16674816);     //                 524,288

    hipLaunchKernelGGL(prep_w2, dim3(448, 32), dim3(64), 0, stream, W, W2);
    hipLaunchKernelGGL(prep_g0, dim3(28, 33), dim3(256), 0, stream, W, embed, bias, G0);
    hipLaunchKernelGGL(prep_init, dim3(512), dim3(256), 0, stream, h0, c0, hs0, c_state, ctgt_state);

    for (int t = 0; t < TT; ++t) {
        const ushort* hr = (t & 1) ? hs1 : hs0;
        ushort*       hw = (t & 1) ? hs0 : hs1;
        hipLaunchKernelGGL(step_kernel, dim3(64), dim3(448), 0, stream,
                           W2, G0, seq_dt, seq_types, hr, hw, c_state, ctgt_state, out, t);
    }
}